// Round 2
// baseline (12024.882 us; speedup 1.0000x reference)
//
#include <hip/hip_runtime.h>

typedef __attribute__((ext_vector_type(8))) short short8v;
typedef __attribute__((ext_vector_type(4))) float f32x4;

#define NB 1024
#define NS 200
#define ND 512
#define NG 1536
#define NM 204800   // NB*NS
#define NFF 256

#define GRU_P 4     // blocks per group (each owns 128 h-cols)
#define GRU_G 64    // groups (each owns 16 batches)

__device__ __forceinline__ float bf2f(unsigned short u){
  union { unsigned u; float f; } v; v.u = ((unsigned)u) << 16; return v.f;
}
__device__ __forceinline__ unsigned short f2bf(float f){
  union { float f; unsigned u; } v; v.f = f;
  unsigned r = v.u + 0x7fffu + ((v.u >> 16) & 1u);
  return (unsigned short)(r >> 16);
}
__device__ __forceinline__ float sigm(float x){ return 1.f / (1.f + __expf(-x)); }
__device__ __forceinline__ float tanhfast(float x){ return 1.f - 2.f / (1.f + __expf(2.f * x)); }

// ---------------- cast f32 -> bf16, 8 elements/thread ----------------
__global__ void k_cast_bf16(const float* __restrict__ in, unsigned short* __restrict__ out, size_t n8){
  size_t i = (size_t)blockIdx.x * blockDim.x + threadIdx.x;
  size_t stride = (size_t)gridDim.x * blockDim.x;
  for (; i < n8; i += stride){
    const float4* p = (const float4*)(in + i * 8);
    float4 a = p[0], b = p[1];
    uint4 v;
    v.x = (unsigned)f2bf(a.x) | ((unsigned)f2bf(a.y) << 16);
    v.y = (unsigned)f2bf(a.z) | ((unsigned)f2bf(a.w) << 16);
    v.z = (unsigned)f2bf(b.x) | ((unsigned)f2bf(b.y) << 16);
    v.w = (unsigned)f2bf(b.z) | ((unsigned)f2bf(b.w) << 16);
    *(uint4*)(out + i * 8) = v;
  }
}

// ---------------- pack W (N x K, row-major, f32) into MFMA B-frag order ----------------
__global__ void k_prepack(const float* __restrict__ W, unsigned short* __restrict__ out,
                          int ld, int coloff, int ntiles){
  int gid = blockIdx.x * 256 + threadIdx.x;
  if (gid >= ntiles * 1024) return;
  int ntile = gid >> 10; int rem = gid & 1023;
  int kk = rem >> 6; int lane = rem & 63;
  int c = ntile * 16 + (lane & 15);
  int k0 = kk * 32 + (lane >> 4) * 8;
  const float* s = W + (size_t)c * ld + coloff + k0;
  uint4 v;
  v.x = (unsigned)f2bf(s[0]) | ((unsigned)f2bf(s[1]) << 16);
  v.y = (unsigned)f2bf(s[2]) | ((unsigned)f2bf(s[3]) << 16);
  v.z = (unsigned)f2bf(s[4]) | ((unsigned)f2bf(s[5]) << 16);
  v.w = (unsigned)f2bf(s[6]) | ((unsigned)f2bf(s[7]) << 16);
  *(uint4*)(out + (size_t)gid * 8) = v;
}

// ---------------- tvec[b][f] = b_fc[f] + sum_d target[b][d] * W_fc[f][512+d] ----------------
__global__ void k_tvec(const float* __restrict__ target, const float* __restrict__ Wfc,
                       const float* __restrict__ bfc, float* __restrict__ tvec){
  __shared__ float tg[4][ND];
  int bb = blockIdx.x;
  int tid = threadIdx.x;
  for (int idx = tid; idx < 4 * ND; idx += 256){
    int j = idx >> 9, d = idx & 511;
    tg[j][d] = target[(size_t)(bb * 4 + j) * ND + d];
  }
  __syncthreads();
  const float* wrow = Wfc + (size_t)tid * 1024 + 512;
  float a0 = 0, a1 = 0, a2 = 0, a3 = 0;
  for (int d = 0; d < ND; ++d){
    float wv = wrow[d];
    a0 += tg[0][d] * wv; a1 += tg[1][d] * wv; a2 += tg[2][d] * wv; a3 += tg[3][d] * wv;
  }
  float bias = bfc[tid];
  tvec[(size_t)(bb * 4 + 0) * NFF + tid] = a0 + bias;
  tvec[(size_t)(bb * 4 + 1) * NFF + tid] = a1 + bias;
  tvec[(size_t)(bb * 4 + 2) * NFF + tid] = a2 + bias;
  tvec[(size_t)(bb * 4 + 3) * NFF + tid] = a3 + bias;
}

// ---------------- gx = hist_bf16 @ W_ih^T + b_ih, output bf16 (NM x 1536) ----------------
__global__ __launch_bounds__(256) void k_gemm_gx(const unsigned short* __restrict__ A,
                                                 const unsigned short* __restrict__ Bpk,
                                                 const float* __restrict__ bih,
                                                 unsigned short* __restrict__ gx){
  __shared__ unsigned short As[128 * 64];
  int tid = threadIdx.x; int lane = tid & 63; int wid = tid >> 6;
  int wm = wid >> 1, wn = wid & 1;
  int Nb = blockIdx.x, Mb = blockIdx.y;
  const unsigned short* Abase = A + (size_t)Mb * 128 * ND;
  const short8v* Bp = (const short8v*)Bpk;
  f32x4 acc[4][4];
  #pragma unroll
  for (int i = 0; i < 4; ++i)
    #pragma unroll
    for (int j = 0; j < 4; ++j) acc[i][j] = (f32x4){0.f, 0.f, 0.f, 0.f};

  for (int kc = 0; kc < 8; ++kc){
    __syncthreads();
    #pragma unroll
    for (int pass = 0; pass < 4; ++pass){
      int idx = pass * 256 + tid; int r = idx >> 3, ch = idx & 7;
      uint4 v = *(const uint4*)(Abase + (size_t)r * ND + kc * 64 + ch * 8);
      *(uint4*)&As[r * 64 + ch * 8] = v;
    }
    __syncthreads();
    #pragma unroll
    for (int i = 0; i < 2; ++i){
      short8v a[4];
      #pragma unroll
      for (int mt = 0; mt < 4; ++mt)
        a[mt] = *(const short8v*)&As[(wm * 64 + mt * 16 + (lane & 15)) * 64 + i * 32 + (lane >> 4) * 8];
      #pragma unroll
      for (int nt = 0; nt < 4; ++nt){
        short8v b = Bp[((size_t)(Nb * 8 + wn * 4 + nt) * 16 + (kc * 2 + i)) * 64 + lane];
        #pragma unroll
        for (int mt = 0; mt < 4; ++mt)
          acc[mt][nt] = __builtin_amdgcn_mfma_f32_16x16x32_bf16(a[mt], b, acc[mt][nt], 0, 0, 0);
      }
    }
  }
  #pragma unroll
  for (int mt = 0; mt < 4; ++mt){
    #pragma unroll
    for (int nt = 0; nt < 4; ++nt){
      int gcol = Nb * 128 + wn * 64 + nt * 16 + (lane & 15);
      float bv = bih[gcol];
      #pragma unroll
      for (int r = 0; r < 4; ++r){
        int grow = Mb * 128 + wm * 64 + mt * 16 + (lane >> 4) * 4 + r;
        gx[(size_t)grow * NG + gcol] = f2bf(acc[mt][nt][r] + bv);
      }
    }
  }
}

// ---------------- GRU recurrence v2: 64 groups x 4 blocks, W_hh slice resident in VGPRs ----------------
// Block owns 128 h-cols (384 gate-cols). 8 waves; wave nh owns 16 h-cols (3 gate tiles r/z/n).
// Per step: MFMA over LDS h-frags -> activations -> write h slice to hx[par] -> flag ->
// spin until all 4 blocks of group flagged -> reload full h into LDS other parity.
__global__ __launch_bounds__(512, 2) void k_gru2(const unsigned short* __restrict__ gx,
                                                 const unsigned short* __restrict__ Wpk,
                                                 const float* __restrict__ bhh,
                                                 unsigned short* __restrict__ gout,
                                                 unsigned short* __restrict__ hx,   // [2][1024*512] bf16
                                                 int* __restrict__ cnt){            // [GRU_G * NS]
  __shared__ unsigned short hbuf[2][16 * 512];   // [parity][16 k-frags of 1KB]
  int tid = threadIdx.x; int lane = tid & 63; int nh = tid >> 6;   // wave 0..7
  int bid = blockIdx.x; int g = bid & 63; int s = bid >> 6;        // group, slice
  int colg = lane & 15;     // col-in-tile / batch-in-frag
  int rowg = lane >> 4;     // row group
  int c_h = s * 128 + nh * 16 + colg;   // this lane's h column
  int b0 = g * 16;                      // group batch base

  for (int i = tid; i < 16 * 512; i += 512) hbuf[0][i] = 0;

  // resident W_hh B-fragments: 3 gate tiles x 16 k-frags = 192 VGPRs
  short8v wf[3][16];
  const short8v* Wp = (const short8v*)Wpk;
  #pragma unroll
  for (int gg = 0; gg < 3; ++gg){
    int ntile = gg * 32 + s * 8 + nh;
    #pragma unroll
    for (int kk = 0; kk < 16; ++kk)
      wf[gg][kk] = Wp[((size_t)ntile * 16 + kk) * 64 + lane];
  }
  float bR = bhh[c_h], bZ = bhh[512 + c_h], bN = bhh[1024 + c_h];
  float hreg[4] = {0.f, 0.f, 0.f, 0.f};
  __syncthreads();

  #pragma unroll 1
  for (int t = 0; t < NS; ++t){
    int par = t & 1;
    // prefetch gx_t (independent of h; consumed after MFMA phase)
    unsigned short uxr[4], uxz[4], uxn[4];
    #pragma unroll
    for (int r = 0; r < 4; ++r){
      const unsigned short* gp = gx + ((size_t)(b0 + rowg * 4 + r) * NS + t) * NG;
      uxr[r] = gp[c_h]; uxz[r] = gp[512 + c_h]; uxn[r] = gp[1024 + c_h];
    }
    // gh = h @ Whh_slice^T
    f32x4 acc[3];
    #pragma unroll
    for (int gg = 0; gg < 3; ++gg) acc[gg] = (f32x4){0.f, 0.f, 0.f, 0.f};
    #pragma unroll
    for (int kc = 0; kc < 16; ++kc){
      short8v a = *(const short8v*)&hbuf[par][kc * 512 + lane * 8];
      acc[0] = __builtin_amdgcn_mfma_f32_16x16x32_bf16(a, wf[0][kc], acc[0], 0, 0, 0);
      acc[1] = __builtin_amdgcn_mfma_f32_16x16x32_bf16(a, wf[1][kc], acc[1], 0, 0, 0);
      acc[2] = __builtin_amdgcn_mfma_f32_16x16x32_bf16(a, wf[2][kc], acc[2], 0, 0, 0);
    }
    // activations; h kept in f32 regs across steps
    unsigned short hnew[4];
    #pragma unroll
    for (int r = 0; r < 4; ++r){
      float rr = sigm(bf2f(uxr[r]) + acc[0][r] + bR);
      float zz = sigm(bf2f(uxz[r]) + acc[1][r] + bZ);
      float nn = tanhfast(bf2f(uxn[r]) + rr * (acc[2][r] + bN));
      float h = nn + zz * (hreg[r] - nn);
      hreg[r] = h;
      hnew[r] = f2bf(h);
    }
    // gout write (always)
    #pragma unroll
    for (int r = 0; r < 4; ++r)
      gout[((size_t)(b0 + rowg * 4 + r) * NS + t) * ND + c_h] = hnew[r];

    if (t + 1 < NS){
      unsigned short* hxp = hx + (size_t)par * (1024 * 512);
      #pragma unroll
      for (int r = 0; r < 4; ++r)
        hxp[(size_t)(b0 + rowg * 4 + r) * 512 + c_h] = hnew[r];
      __syncthreads();   // all waves' stores issued+drained (barrier drains vmcnt)
      if (tid == 0){
        __threadfence();  // make group-visible (L2 writeback, device scope)
        __hip_atomic_fetch_add(&cnt[g * NS + t], 1, __ATOMIC_RELEASE, __HIP_MEMORY_SCOPE_AGENT);
      }
      if (lane == 0){
        while (__hip_atomic_load(&cnt[g * NS + t], __ATOMIC_ACQUIRE, __HIP_MEMORY_SCOPE_AGENT) < GRU_P)
          __builtin_amdgcn_s_sleep(1);
      }
      // reload full h_t into other parity LDS; wave nh stages k-frags 2nh, 2nh+1
      #pragma unroll
      for (int j = 0; j < 2; ++j){
        int kc = nh * 2 + j;
        const unsigned short* src = hxp + (size_t)(b0 + colg) * 512 + kc * 32 + rowg * 8;
        uint4 v = *(const uint4*)src;
        *(uint4*)&hbuf[par ^ 1][kc * 512 + lane * 8] = v;
      }
      __syncthreads();
    }
  }
}

// ---------------- pre/GELU/scores fused GEMM: (NM x 512) @ Wg^T (256) ----------------
__global__ __launch_bounds__(512) void k_gemm_s4(const unsigned short* __restrict__ A,
                                                 const unsigned short* __restrict__ Bpk,
                                                 const float* __restrict__ tvec,
                                                 const float* __restrict__ Wsc,
                                                 const float* __restrict__ bsc,
                                                 float* __restrict__ scores){
  __shared__ unsigned short As[128 * 64];
  __shared__ float spart[4][128];
  int tid = threadIdx.x; int lane = tid & 63; int wid = tid >> 6;
  int wm = wid >> 2, wn = wid & 3;
  int Mb = blockIdx.x;
  const unsigned short* Abase = A + (size_t)Mb * 128 * ND;
  const short8v* Bp = (const short8v*)Bpk;
  f32x4 acc[4][4];
  #pragma unroll
  for (int i = 0; i < 4; ++i)
    #pragma unroll
    for (int j = 0; j < 4; ++j) acc[i][j] = (f32x4){0.f, 0.f, 0.f, 0.f};

  for (int kc = 0; kc < 8; ++kc){
    __syncthreads();
    #pragma unroll
    for (int pass = 0; pass < 2; ++pass){
      int idx = pass * 512 + tid; int r = idx >> 3, ch = idx & 7;
      uint4 v = *(const uint4*)(Abase + (size_t)r * ND + kc * 64 + ch * 8);
      *(uint4*)&As[r * 64 + ch * 8] = v;
    }
    __syncthreads();
    #pragma unroll
    for (int i = 0; i < 2; ++i){
      short8v a[4];
      #pragma unroll
      for (int mt = 0; mt < 4; ++mt)
        a[mt] = *(const short8v*)&As[(wm * 64 + mt * 16 + (lane & 15)) * 64 + i * 32 + (lane >> 4) * 8];
      #pragma unroll
      for (int nt = 0; nt < 4; ++nt){
        short8v b = Bp[((size_t)(wn * 4 + nt) * 16 + (kc * 2 + i)) * 64 + lane];
        #pragma unroll
        for (int mt = 0; mt < 4; ++mt)
          acc[mt][nt] = __builtin_amdgcn_mfma_f32_16x16x32_bf16(a[mt], b, acc[mt][nt], 0, 0, 0);
      }
    }
  }
  #pragma unroll
  for (int mt = 0; mt < 4; ++mt){
    #pragma unroll
    for (int r = 0; r < 4; ++r){
      int rowl = wm * 64 + mt * 16 + (lane >> 4) * 4 + r;
      unsigned grow = (unsigned)(Mb * 128 + rowl);
      unsigned bidx = grow / 200u;
      float rowsum = 0.f;
      #pragma unroll
      for (int nt = 0; nt < 4; ++nt){
        int gcol = wn * 64 + nt * 16 + (lane & 15);
        float pre = acc[mt][nt][r] + tvec[(size_t)bidx * NFF + gcol];
        float g = 0.5f * pre * (1.f + erff(pre * 0.70710678118654752f));
        rowsum += g * Wsc[gcol];
      }
      rowsum += __shfl_xor(rowsum, 1, 64);
      rowsum += __shfl_xor(rowsum, 2, 64);
      rowsum += __shfl_xor(rowsum, 4, 64);
      rowsum += __shfl_xor(rowsum, 8, 64);
      if ((lane & 15) == 0) spart[wn][rowl] = rowsum;
    }
  }
  __syncthreads();
  if (tid < 128){
    float s = spart[0][tid] + spart[1][tid] + spart[2][tid] + spart[3][tid] + bsc[0];
    scores[(size_t)Mb * 128 + tid] = s;
  }
}

// ---------------- softmax over S + weighted pool + concat output ----------------
__global__ void k_out(const float* __restrict__ scores, const unsigned short* __restrict__ gout,
                      const float* __restrict__ target, float* __restrict__ out){
  int b = blockIdx.x; int tid = threadIdx.x;
  __shared__ float sw[NS];
  __shared__ float red[4];
  float v = (tid < NS) ? scores[(size_t)b * NS + tid] : -3.0e38f;
  float m = v;
  #pragma unroll
  for (int off = 32; off >= 1; off >>= 1) m = fmaxf(m, __shfl_xor(m, off, 64));
  if ((tid & 63) == 0) red[tid >> 6] = m;
  __syncthreads();
  m = fmaxf(fmaxf(red[0], red[1]), fmaxf(red[2], red[3]));
  float e = (tid < NS) ? __expf(v - m) : 0.f;
  if (tid < NS) sw[tid] = e;
  float su = e;
  #pragma unroll
  for (int off = 32; off >= 1; off >>= 1) su += __shfl_xor(su, off, 64);
  __syncthreads();
  if ((tid & 63) == 0) red[tid >> 6] = su;
  __syncthreads();
  float inv = 1.f / (red[0] + red[1] + red[2] + red[3]);
  int d0 = tid * 2;
  float a0 = 0.f, a1 = 0.f;
  const unsigned short* gbase = gout + (size_t)b * NS * ND + d0;
  for (int s = 0; s < NS; ++s){
    unsigned u = *(const unsigned*)(gbase + (size_t)s * ND);
    float wgt = sw[s];
    a0 += wgt * bf2f((unsigned short)(u & 0xffffu));
    a1 += wgt * bf2f((unsigned short)(u >> 16));
  }
  out[(size_t)b * 1024 + d0] = a0 * inv;
  out[(size_t)b * 1024 + d0 + 1] = a1 * inv;
  float2 tv = *(const float2*)(target + (size_t)b * ND + d0);
  out[(size_t)b * 1024 + 512 + d0] = tv.x;
  out[(size_t)b * 1024 + 512 + d0 + 1] = tv.y;
}

extern "C" void kernel_launch(void* const* d_in, const int* in_sizes, int n_in,
                              void* d_out, int out_size, void* d_ws, size_t ws_size,
                              hipStream_t stream) {
  const float* target  = (const float*)d_in[0];
  const float* history = (const float*)d_in[1];
  const float* W_ih    = (const float*)d_in[2];
  const float* W_hh    = (const float*)d_in[3];
  const float* b_ih    = (const float*)d_in[4];
  const float* b_hh    = (const float*)d_in[5];
  const float* W_fc    = (const float*)d_in[6];
  const float* b_fc    = (const float*)d_in[7];
  const float* W_sc    = (const float*)d_in[8];
  const float* b_sc    = (const float*)d_in[9];

  char* ws = (char*)d_ws;
  size_t off = 0;
  unsigned short* histb  = (unsigned short*)(ws + off); off += 209715200ull;  // NM*512 bf16
  unsigned short* gx     = (unsigned short*)(ws + off); off += 629145600ull;  // NM*1536 bf16
  unsigned short* gout   = (unsigned short*)(ws + off); off += 209715200ull;  // NM*512 bf16
  unsigned short* wih_pk = (unsigned short*)(ws + off); off += 1572864ull;
  unsigned short* whh_pk = (unsigned short*)(ws + off); off += 1572864ull;
  unsigned short* wg_pk  = (unsigned short*)(ws + off); off += 262144ull;
  float*          tvec   = (float*)(ws + off);          off += 1048576ull;
  float*          scores = (float*)(ws + off);          off += 819200ull;
  unsigned short* hx     = (unsigned short*)(ws + off); off += 2097152ull;    // [2][1024*512] bf16
  int*            cnt    = (int*)(ws + off);             off += 65536ull;      // [64*200] flags
  if (ws_size < off) return;
  float* outp = (float*)d_out;

  hipMemsetAsync(cnt, 0, GRU_G * NS * sizeof(int), stream);
  k_cast_bf16<<<2048, 256, 0, stream>>>(history, histb, (size_t)13107200ull);
  k_prepack<<<384, 256, 0, stream>>>(W_ih, wih_pk, 512, 0, 96);
  k_prepack<<<384, 256, 0, stream>>>(W_hh, whh_pk, 512, 0, 96);
  k_prepack<<<64, 256, 0, stream>>>(W_fc, wg_pk, 1024, 0, 16);
  k_tvec<<<256, 256, 0, stream>>>(target, W_fc, b_fc, tvec);
  k_gemm_gx<<<dim3(12, 1600), 256, 0, stream>>>(histb, wih_pk, b_ih, gx);
  k_gru2<<<256, 512, 0, stream>>>(gx, whh_pk, b_hh, gout, hx, cnt);
  k_gemm_s4<<<1600, 512, 0, stream>>>(gout, wg_pk, tvec, W_sc, b_sc, scores);
  k_out<<<1024, 256, 0, stream>>>(scores, gout, target, outp);
}

// Round 3
// 2728.409 us; speedup vs baseline: 4.4073x; 4.4073x over previous
//
#include <hip/hip_runtime.h>

typedef __attribute__((ext_vector_type(8))) short short8v;
typedef __attribute__((ext_vector_type(4))) float f32x4;

#define NB 1024
#define NS 200
#define ND 512
#define NG 1536
#define NM 204800   // NB*NS
#define NFF 256

#define GRU_P 4     // blocks per group (each owns 128 h-cols)
#define GRU_G 64    // groups (each owns 16 batches)

__device__ __forceinline__ float bf2f(unsigned short u){
  union { unsigned u; float f; } v; v.u = ((unsigned)u) << 16; return v.f;
}
__device__ __forceinline__ unsigned short f2bf(float f){
  union { float f; unsigned u; } v; v.f = f;
  unsigned r = v.u + 0x7fffu + ((v.u >> 16) & 1u);
  return (unsigned short)(r >> 16);
}
__device__ __forceinline__ float sigm(float x){ return 1.f / (1.f + __expf(-x)); }
__device__ __forceinline__ float tanhfast(float x){ return 1.f - 2.f / (1.f + __expf(2.f * x)); }

// ---------------- cast f32 -> bf16, 8 elements/thread ----------------
__global__ void k_cast_bf16(const float* __restrict__ in, unsigned short* __restrict__ out, size_t n8){
  size_t i = (size_t)blockIdx.x * blockDim.x + threadIdx.x;
  size_t stride = (size_t)gridDim.x * blockDim.x;
  for (; i < n8; i += stride){
    const float4* p = (const float4*)(in + i * 8);
    float4 a = p[0], b = p[1];
    uint4 v;
    v.x = (unsigned)f2bf(a.x) | ((unsigned)f2bf(a.y) << 16);
    v.y = (unsigned)f2bf(a.z) | ((unsigned)f2bf(a.w) << 16);
    v.z = (unsigned)f2bf(b.x) | ((unsigned)f2bf(b.y) << 16);
    v.w = (unsigned)f2bf(b.z) | ((unsigned)f2bf(b.w) << 16);
    *(uint4*)(out + i * 8) = v;
  }
}

// ---------------- pack W (N x K, row-major, f32) into MFMA B-frag order ----------------
__global__ void k_prepack(const float* __restrict__ W, unsigned short* __restrict__ out,
                          int ld, int coloff, int ntiles){
  int gid = blockIdx.x * 256 + threadIdx.x;
  if (gid >= ntiles * 1024) return;
  int ntile = gid >> 10; int rem = gid & 1023;
  int kk = rem >> 6; int lane = rem & 63;
  int c = ntile * 16 + (lane & 15);
  int k0 = kk * 32 + (lane >> 4) * 8;
  const float* s = W + (size_t)c * ld + coloff + k0;
  uint4 v;
  v.x = (unsigned)f2bf(s[0]) | ((unsigned)f2bf(s[1]) << 16);
  v.y = (unsigned)f2bf(s[2]) | ((unsigned)f2bf(s[3]) << 16);
  v.z = (unsigned)f2bf(s[4]) | ((unsigned)f2bf(s[5]) << 16);
  v.w = (unsigned)f2bf(s[6]) | ((unsigned)f2bf(s[7]) << 16);
  *(uint4*)(out + (size_t)gid * 8) = v;
}

// ---------------- tvec[b][f] = b_fc[f] + sum_d target[b][d] * W_fc[f][512+d] ----------------
__global__ void k_tvec(const float* __restrict__ target, const float* __restrict__ Wfc,
                       const float* __restrict__ bfc, float* __restrict__ tvec){
  __shared__ float tg[4][ND];
  int bb = blockIdx.x;
  int tid = threadIdx.x;
  for (int idx = tid; idx < 4 * ND; idx += 256){
    int j = idx >> 9, d = idx & 511;
    tg[j][d] = target[(size_t)(bb * 4 + j) * ND + d];
  }
  __syncthreads();
  const float* wrow = Wfc + (size_t)tid * 1024 + 512;
  float a0 = 0, a1 = 0, a2 = 0, a3 = 0;
  for (int d = 0; d < ND; ++d){
    float wv = wrow[d];
    a0 += tg[0][d] * wv; a1 += tg[1][d] * wv; a2 += tg[2][d] * wv; a3 += tg[3][d] * wv;
  }
  float bias = bfc[tid];
  tvec[(size_t)(bb * 4 + 0) * NFF + tid] = a0 + bias;
  tvec[(size_t)(bb * 4 + 1) * NFF + tid] = a1 + bias;
  tvec[(size_t)(bb * 4 + 2) * NFF + tid] = a2 + bias;
  tvec[(size_t)(bb * 4 + 3) * NFF + tid] = a3 + bias;
}

// ---------------- gx = hist_bf16 @ W_ih^T + b_ih, output bf16 (NM x 1536) ----------------
__global__ __launch_bounds__(256) void k_gemm_gx(const unsigned short* __restrict__ A,
                                                 const unsigned short* __restrict__ Bpk,
                                                 const float* __restrict__ bih,
                                                 unsigned short* __restrict__ gx){
  __shared__ unsigned short As[128 * 64];
  int tid = threadIdx.x; int lane = tid & 63; int wid = tid >> 6;
  int wm = wid >> 1, wn = wid & 1;
  int Nb = blockIdx.x, Mb = blockIdx.y;
  const unsigned short* Abase = A + (size_t)Mb * 128 * ND;
  const short8v* Bp = (const short8v*)Bpk;
  f32x4 acc[4][4];
  #pragma unroll
  for (int i = 0; i < 4; ++i)
    #pragma unroll
    for (int j = 0; j < 4; ++j) acc[i][j] = (f32x4){0.f, 0.f, 0.f, 0.f};

  for (int kc = 0; kc < 8; ++kc){
    __syncthreads();
    #pragma unroll
    for (int pass = 0; pass < 4; ++pass){
      int idx = pass * 256 + tid; int r = idx >> 3, ch = idx & 7;
      uint4 v = *(const uint4*)(Abase + (size_t)r * ND + kc * 64 + ch * 8);
      *(uint4*)&As[r * 64 + ch * 8] = v;
    }
    __syncthreads();
    #pragma unroll
    for (int i = 0; i < 2; ++i){
      short8v a[4];
      #pragma unroll
      for (int mt = 0; mt < 4; ++mt)
        a[mt] = *(const short8v*)&As[(wm * 64 + mt * 16 + (lane & 15)) * 64 + i * 32 + (lane >> 4) * 8];
      #pragma unroll
      for (int nt = 0; nt < 4; ++nt){
        short8v b = Bp[((size_t)(Nb * 8 + wn * 4 + nt) * 16 + (kc * 2 + i)) * 64 + lane];
        #pragma unroll
        for (int mt = 0; mt < 4; ++mt)
          acc[mt][nt] = __builtin_amdgcn_mfma_f32_16x16x32_bf16(a[mt], b, acc[mt][nt], 0, 0, 0);
      }
    }
  }
  #pragma unroll
  for (int mt = 0; mt < 4; ++mt){
    #pragma unroll
    for (int nt = 0; nt < 4; ++nt){
      int gcol = Nb * 128 + wn * 64 + nt * 16 + (lane & 15);
      float bv = bih[gcol];
      #pragma unroll
      for (int r = 0; r < 4; ++r){
        int grow = Mb * 128 + wm * 64 + mt * 16 + (lane >> 4) * 4 + r;
        gx[(size_t)grow * NG + gcol] = f2bf(acc[mt][nt][r] + bv);
      }
    }
  }
}

// ---------------- GRU recurrence v3 ----------------
// 64 groups x 4 blocks; block owns 128 h-cols; W_hh slice resident in VGPRs
// (launch_bounds(512,1) -> 256-VGPR cap, wf[3][16]=192 regs fits).
// Cross-block h exchange via fine-grained coherent (relaxed, agent-scope)
// loads/stores -> serviced past L2, NO buffer_wbl2/buffer_inv storms.
__global__ __launch_bounds__(512, 1) void k_gru3(const unsigned short* __restrict__ gx,
                                                 const unsigned short* __restrict__ Wpk,
                                                 const float* __restrict__ bhh,
                                                 unsigned short* __restrict__ gout,
                                                 unsigned long long* __restrict__ hx,  // [2][1024*128] ulong
                                                 int* __restrict__ cnt){               // [GRU_G * NS]
  __shared__ unsigned short hbuf[2][16 * 512];   // [parity][16 k-frags of 1KB]
  __shared__ unsigned short hstage[8][16][16];   // per-wave repack buffer
  int tid = threadIdx.x; int lane = tid & 63; int nh = tid >> 6;   // wave 0..7
  int bid = blockIdx.x; int g = bid & 63; int s = bid >> 6;        // group, slice
  int colg = lane & 15;
  int rowg = lane >> 4;
  int c_h = s * 128 + nh * 16 + colg;   // this lane's h column
  int b0 = g * 16;                      // group batch base

  for (int i = tid; i < 16 * 512; i += 512) hbuf[0][i] = 0;

  // resident W_hh B-fragments: 3 gate tiles x 16 k-frags = 192 VGPRs
  short8v wf[3][16];
  const short8v* Wp = (const short8v*)Wpk;
  #pragma unroll
  for (int gg = 0; gg < 3; ++gg){
    int ntile = gg * 32 + s * 8 + nh;
    #pragma unroll
    for (int kk = 0; kk < 16; ++kk)
      wf[gg][kk] = Wp[((size_t)ntile * 16 + kk) * 64 + lane];
  }
  float bR = bhh[c_h], bZ = bhh[512 + c_h], bN = bhh[1024 + c_h];
  float hreg[4] = {0.f, 0.f, 0.f, 0.f};
  __syncthreads();

  #pragma unroll 1
  for (int t = 0; t < NS; ++t){
    int par = t & 1;
    const unsigned short* hr = hbuf[par];
    unsigned short* hw = hbuf[par ^ 1];
    // prefetch gx_t (independent of h; consumed after MFMA phase)
    unsigned short uxr[4], uxz[4], uxn[4];
    #pragma unroll
    for (int r = 0; r < 4; ++r){
      const unsigned short* gp = gx + ((size_t)(b0 + rowg * 4 + r) * NS + t) * NG;
      uxr[r] = gp[c_h]; uxz[r] = gp[512 + c_h]; uxn[r] = gp[1024 + c_h];
    }
    // gh = h @ Whh_slice^T
    f32x4 acc0 = (f32x4){0.f,0.f,0.f,0.f}, acc1 = acc0, acc2 = acc0;
    #pragma unroll
    for (int kc = 0; kc < 16; ++kc){
      short8v a = *(const short8v*)&hr[kc * 512 + lane * 8];
      acc0 = __builtin_amdgcn_mfma_f32_16x16x32_bf16(a, wf[0][kc], acc0, 0, 0, 0);
      acc1 = __builtin_amdgcn_mfma_f32_16x16x32_bf16(a, wf[1][kc], acc1, 0, 0, 0);
      acc2 = __builtin_amdgcn_mfma_f32_16x16x32_bf16(a, wf[2][kc], acc2, 0, 0, 0);
    }
    // activations; h kept in f32 regs across steps
    unsigned short hnew[4];
    #pragma unroll
    for (int r = 0; r < 4; ++r){
      float rr = sigm(bf2f(uxr[r]) + acc0[r] + bR);
      float zz = sigm(bf2f(uxz[r]) + acc1[r] + bZ);
      float nn = tanhfast(bf2f(uxn[r]) + rr * (acc2[r] + bN));
      float h = nn + zz * (hreg[r] - nn);
      hreg[r] = h;
      hnew[r] = f2bf(h);
    }

    if (t + 1 < NS){
      unsigned long long* hxp = hx + (size_t)par * (1024 * 128);
      // pack this wave's 16x16 slice in LDS, then coherent-store as ulongs
      #pragma unroll
      for (int r = 0; r < 4; ++r) hstage[nh][rowg * 4 + r][colg] = hnew[r];
      asm volatile("s_waitcnt lgkmcnt(0)" ::: "memory");
      {
        int bl = lane >> 2, cq = lane & 3;
        unsigned long long v = *(const unsigned long long*)&hstage[nh][bl][cq * 4];
        __hip_atomic_store(&hxp[(size_t)(b0 + bl) * 128 + s * 32 + nh * 4 + cq], v,
                           __ATOMIC_RELAXED, __HIP_MEMORY_SCOPE_AGENT);
      }
      __syncthreads();   // drains vmcnt: all slice stores complete at coherence point
      if (tid == 0)
        __hip_atomic_fetch_add(&cnt[g * NS + t], 1, __ATOMIC_RELAXED, __HIP_MEMORY_SCOPE_AGENT);
      // gout write overlaps the spin
      #pragma unroll
      for (int r = 0; r < 4; ++r)
        gout[((size_t)(b0 + rowg * 4 + r) * NS + t) * ND + c_h] = hnew[r];
      if (lane == 0){
        while (__hip_atomic_load(&cnt[g * NS + t], __ATOMIC_RELAXED, __HIP_MEMORY_SCOPE_AGENT) < GRU_P)
          __builtin_amdgcn_s_sleep(1);
      }
      asm volatile("" ::: "memory");
      // reload full h_t into other-parity LDS in MFMA A-frag layout
      #pragma unroll
      for (int q = 0; q < 2; ++q){
        int idx = tid + q * 512;           // 0..1023 frag-slots
        int kc = idx >> 6, ls = idx & 63;
        int batch = ls & 15, kq = ls >> 4;
        size_t base = (size_t)(b0 + batch) * 128 + kc * 8 + kq * 2;
        unsigned long long u0 = __hip_atomic_load(&hxp[base],     __ATOMIC_RELAXED, __HIP_MEMORY_SCOPE_AGENT);
        unsigned long long u1 = __hip_atomic_load(&hxp[base + 1], __ATOMIC_RELAXED, __HIP_MEMORY_SCOPE_AGENT);
        unsigned long long tmp[2] = {u0, u1};
        *(uint4*)&hw[kc * 512 + ls * 8] = *(const uint4*)tmp;
      }
      __syncthreads();
    } else {
      #pragma unroll
      for (int r = 0; r < 4; ++r)
        gout[((size_t)(b0 + rowg * 4 + r) * NS + t) * ND + c_h] = hnew[r];
    }
  }
}

// ---------------- pre/GELU/scores fused GEMM: (NM x 512) @ Wg^T (256) ----------------
__global__ __launch_bounds__(512) void k_gemm_s4(const unsigned short* __restrict__ A,
                                                 const unsigned short* __restrict__ Bpk,
                                                 const float* __restrict__ tvec,
                                                 const float* __restrict__ Wsc,
                                                 const float* __restrict__ bsc,
                                                 float* __restrict__ scores){
  __shared__ unsigned short As[128 * 64];
  __shared__ float spart[4][128];
  int tid = threadIdx.x; int lane = tid & 63; int wid = tid >> 6;
  int wm = wid >> 2, wn = wid & 3;
  int Mb = blockIdx.x;
  const unsigned short* Abase = A + (size_t)Mb * 128 * ND;
  const short8v* Bp = (const short8v*)Bpk;
  f32x4 acc[4][4];
  #pragma unroll
  for (int i = 0; i < 4; ++i)
    #pragma unroll
    for (int j = 0; j < 4; ++j) acc[i][j] = (f32x4){0.f, 0.f, 0.f, 0.f};

  for (int kc = 0; kc < 8; ++kc){
    __syncthreads();
    #pragma unroll
    for (int pass = 0; pass < 2; ++pass){
      int idx = pass * 512 + tid; int r = idx >> 3, ch = idx & 7;
      uint4 v = *(const uint4*)(Abase + (size_t)r * ND + kc * 64 + ch * 8);
      *(uint4*)&As[r * 64 + ch * 8] = v;
    }
    __syncthreads();
    #pragma unroll
    for (int i = 0; i < 2; ++i){
      short8v a[4];
      #pragma unroll
      for (int mt = 0; mt < 4; ++mt)
        a[mt] = *(const short8v*)&As[(wm * 64 + mt * 16 + (lane & 15)) * 64 + i * 32 + (lane >> 4) * 8];
      #pragma unroll
      for (int nt = 0; nt < 4; ++nt){
        short8v b = Bp[((size_t)(wn * 4 + nt) * 16 + (kc * 2 + i)) * 64 + lane];
        #pragma unroll
        for (int mt = 0; mt < 4; ++mt)
          acc[mt][nt] = __builtin_amdgcn_mfma_f32_16x16x32_bf16(a[mt], b, acc[mt][nt], 0, 0, 0);
      }
    }
  }
  #pragma unroll
  for (int mt = 0; mt < 4; ++mt){
    #pragma unroll
    for (int r = 0; r < 4; ++r){
      int rowl = wm * 64 + mt * 16 + (lane >> 4) * 4 + r;
      unsigned grow = (unsigned)(Mb * 128 + rowl);
      unsigned bidx = grow / 200u;
      float rowsum = 0.f;
      #pragma unroll
      for (int nt = 0; nt < 4; ++nt){
        int gcol = wn * 64 + nt * 16 + (lane & 15);
        float pre = acc[mt][nt][r] + tvec[(size_t)bidx * NFF + gcol];
        float g = 0.5f * pre * (1.f + erff(pre * 0.70710678118654752f));
        rowsum += g * Wsc[gcol];
      }
      rowsum += __shfl_xor(rowsum, 1, 64);
      rowsum += __shfl_xor(rowsum, 2, 64);
      rowsum += __shfl_xor(rowsum, 4, 64);
      rowsum += __shfl_xor(rowsum, 8, 64);
      if ((lane & 15) == 0) spart[wn][rowl] = rowsum;
    }
  }
  __syncthreads();
  if (tid < 128){
    float s = spart[0][tid] + spart[1][tid] + spart[2][tid] + spart[3][tid] + bsc[0];
    scores[(size_t)Mb * 128 + tid] = s;
  }
}

// ---------------- softmax over S + weighted pool + concat output ----------------
__global__ void k_out(const float* __restrict__ scores, const unsigned short* __restrict__ gout,
                      const float* __restrict__ target, float* __restrict__ out){
  int b = blockIdx.x; int tid = threadIdx.x;
  __shared__ float sw[NS];
  __shared__ float red[4];
  float v = (tid < NS) ? scores[(size_t)b * NS + tid] : -3.0e38f;
  float m = v;
  #pragma unroll
  for (int off = 32; off >= 1; off >>= 1) m = fmaxf(m, __shfl_xor(m, off, 64));
  if ((tid & 63) == 0) red[tid >> 6] = m;
  __syncthreads();
  m = fmaxf(fmaxf(red[0], red[1]), fmaxf(red[2], red[3]));
  float e = (tid < NS) ? __expf(v - m) : 0.f;
  if (tid < NS) sw[tid] = e;
  float su = e;
  #pragma unroll
  for (int off = 32; off >= 1; off >>= 1) su += __shfl_xor(su, off, 64);
  __syncthreads();
  if ((tid & 63) == 0) red[tid >> 6] = su;
  __syncthreads();
  float inv = 1.f / (red[0] + red[1] + red[2] + red[3]);
  int d0 = tid * 2;
  float a0 = 0.f, a1 = 0.f;
  const unsigned short* gbase = gout + (size_t)b * NS * ND + d0;
  for (int s = 0; s < NS; ++s){
    unsigned u = *(const unsigned*)(gbase + (size_t)s * ND);
    float wgt = sw[s];
    a0 += wgt * bf2f((unsigned short)(u & 0xffffu));
    a1 += wgt * bf2f((unsigned short)(u >> 16));
  }
  out[(size_t)b * 1024 + d0] = a0 * inv;
  out[(size_t)b * 1024 + d0 + 1] = a1 * inv;
  float2 tv = *(const float2*)(target + (size_t)b * ND + d0);
  out[(size_t)b * 1024 + 512 + d0] = tv.x;
  out[(size_t)b * 1024 + 512 + d0 + 1] = tv.y;
}

extern "C" void kernel_launch(void* const* d_in, const int* in_sizes, int n_in,
                              void* d_out, int out_size, void* d_ws, size_t ws_size,
                              hipStream_t stream) {
  const float* target  = (const float*)d_in[0];
  const float* history = (const float*)d_in[1];
  const float* W_ih    = (const float*)d_in[2];
  const float* W_hh    = (const float*)d_in[3];
  const float* b_ih    = (const float*)d_in[4];
  const float* b_hh    = (const float*)d_in[5];
  const float* W_fc    = (const float*)d_in[6];
  const float* b_fc    = (const float*)d_in[7];
  const float* W_sc    = (const float*)d_in[8];
  const float* b_sc    = (const float*)d_in[9];

  char* ws = (char*)d_ws;
  size_t off = 0;
  unsigned short* histb  = (unsigned short*)(ws + off); off += 209715200ull;  // NM*512 bf16
  unsigned short* gx     = (unsigned short*)(ws + off); off += 629145600ull;  // NM*1536 bf16
  unsigned short* gout   = (unsigned short*)(ws + off); off += 209715200ull;  // NM*512 bf16
  unsigned short* wih_pk = (unsigned short*)(ws + off); off += 1572864ull;
  unsigned short* whh_pk = (unsigned short*)(ws + off); off += 1572864ull;
  unsigned short* wg_pk  = (unsigned short*)(ws + off); off += 262144ull;
  float*          tvec   = (float*)(ws + off);          off += 1048576ull;
  float*          scores = (float*)(ws + off);          off += 819200ull;
  unsigned long long* hx = (unsigned long long*)(ws + off); off += 2097152ull; // [2][1024*128] u64
  int*            cnt    = (int*)(ws + off);             off += 65536ull;       // [64*200] flags
  if (ws_size < off) return;
  float* outp = (float*)d_out;

  hipMemsetAsync(cnt, 0, GRU_G * NS * sizeof(int), stream);
  k_cast_bf16<<<2048, 256, 0, stream>>>(history, histb, (size_t)13107200ull);
  k_prepack<<<384, 256, 0, stream>>>(W_ih, wih_pk, 512, 0, 96);
  k_prepack<<<384, 256, 0, stream>>>(W_hh, whh_pk, 512, 0, 96);
  k_prepack<<<64, 256, 0, stream>>>(W_fc, wg_pk, 1024, 0, 16);
  k_tvec<<<256, 256, 0, stream>>>(target, W_fc, b_fc, tvec);
  k_gemm_gx<<<dim3(12, 1600), 256, 0, stream>>>(histb, wih_pk, b_ih, gx);
  k_gru3<<<256, 512, 0, stream>>>(gx, whh_pk, b_hh, gout, hx, cnt);
  k_gemm_s4<<<1600, 512, 0, stream>>>(gout, wg_pk, tvec, W_sc, b_sc, scores);
  k_out<<<1024, 256, 0, stream>>>(scores, gout, target, outp);
}

// Round 4
// 2280.365 us; speedup vs baseline: 5.2732x; 1.1965x over previous
//
#include <hip/hip_runtime.h>

typedef __attribute__((ext_vector_type(8))) short short8v;
typedef __attribute__((ext_vector_type(4))) float f32x4;

#define NB 1024
#define NS 200
#define ND 512
#define NG 1536
#define NM 204800   // NB*NS
#define NFF 256

#define GRU_P 4     // blocks per group (each owns 128 h-cols)
#define GRU_G 64    // groups (each owns 16 batches)

__device__ __forceinline__ float bf2f(unsigned short u){
  union { unsigned u; float f; } v; v.u = ((unsigned)u) << 16; return v.f;
}
__device__ __forceinline__ unsigned short f2bf(float f){
  union { float f; unsigned u; } v; v.f = f;
  unsigned r = v.u + 0x7fffu + ((v.u >> 16) & 1u);
  return (unsigned short)(r >> 16);
}
__device__ __forceinline__ float sigm(float x){ return 1.f / (1.f + __expf(-x)); }
__device__ __forceinline__ float tanhfast(float x){ return 1.f - 2.f / (1.f + __expf(2.f * x)); }

// ---------------- pack W (N x K, row-major, f32) into MFMA B-frag order ----------------
__global__ void k_prepack(const float* __restrict__ W, unsigned short* __restrict__ out,
                          int ld, int coloff, int ntiles){
  int gid = blockIdx.x * 256 + threadIdx.x;
  if (gid >= ntiles * 1024) return;
  int ntile = gid >> 10; int rem = gid & 1023;
  int kk = rem >> 6; int lane = rem & 63;
  int c = ntile * 16 + (lane & 15);
  int k0 = kk * 32 + (lane >> 4) * 8;
  const float* s = W + (size_t)c * ld + coloff + k0;
  uint4 v;
  v.x = (unsigned)f2bf(s[0]) | ((unsigned)f2bf(s[1]) << 16);
  v.y = (unsigned)f2bf(s[2]) | ((unsigned)f2bf(s[3]) << 16);
  v.z = (unsigned)f2bf(s[4]) | ((unsigned)f2bf(s[5]) << 16);
  v.w = (unsigned)f2bf(s[6]) | ((unsigned)f2bf(s[7]) << 16);
  *(uint4*)(out + (size_t)gid * 8) = v;
}

// ---------------- tvec[b][f] = b_fc[f] + sum_d target[b][d] * W_fc[f][512+d] ----------------
__global__ void k_tvec(const float* __restrict__ target, const float* __restrict__ Wfc,
                       const float* __restrict__ bfc, float* __restrict__ tvec){
  __shared__ float tg[4][ND];
  int bb = blockIdx.x;
  int tid = threadIdx.x;
  for (int idx = tid; idx < 4 * ND; idx += 256){
    int j = idx >> 9, d = idx & 511;
    tg[j][d] = target[(size_t)(bb * 4 + j) * ND + d];
  }
  __syncthreads();
  const float* wrow = Wfc + (size_t)tid * 1024 + 512;
  float a0 = 0, a1 = 0, a2 = 0, a3 = 0;
  for (int d = 0; d < ND; ++d){
    float wv = wrow[d];
    a0 += tg[0][d] * wv; a1 += tg[1][d] * wv; a2 += tg[2][d] * wv; a3 += tg[3][d] * wv;
  }
  float bias = bfc[tid];
  tvec[(size_t)(bb * 4 + 0) * NFF + tid] = a0 + bias;
  tvec[(size_t)(bb * 4 + 1) * NFF + tid] = a1 + bias;
  tvec[(size_t)(bb * 4 + 2) * NFF + tid] = a2 + bias;
  tvec[(size_t)(bb * 4 + 3) * NFF + tid] = a3 + bias;
}

// ---------------- gx = history(f32) @ W_ih^T + b_ih, output bf16 (NM x 1536) ----------------
// f32 A staged with in-register bf16 pack (cast fused), 128x128 tile, BK=64, 4 waves.
__global__ __launch_bounds__(256) void k_gemm_gx(const float* __restrict__ Af,
                                                 const unsigned short* __restrict__ Bpk,
                                                 const float* __restrict__ bih,
                                                 unsigned short* __restrict__ gx){
  __shared__ unsigned short As[128 * 64];
  int tid = threadIdx.x; int lane = tid & 63; int wid = tid >> 6;
  int wm = wid >> 1, wn = wid & 1;
  int Nb = blockIdx.x, Mb = blockIdx.y;
  const float* Abase = Af + (size_t)Mb * 128 * ND;
  const short8v* Bp = (const short8v*)Bpk;
  f32x4 acc[4][4];
  #pragma unroll
  for (int i = 0; i < 4; ++i)
    #pragma unroll
    for (int j = 0; j < 4; ++j) acc[i][j] = (f32x4){0.f, 0.f, 0.f, 0.f};

  for (int kc = 0; kc < 8; ++kc){
    __syncthreads();
    #pragma unroll
    for (int pass = 0; pass < 4; ++pass){
      int idx = pass * 256 + tid; int r = idx >> 3, ch = idx & 7;
      const float* src = Abase + (size_t)r * ND + kc * 64 + ch * 8;
      float4 f0 = *(const float4*)src;
      float4 f1 = *(const float4*)(src + 4);
      uint4 v;
      v.x = (unsigned)f2bf(f0.x) | ((unsigned)f2bf(f0.y) << 16);
      v.y = (unsigned)f2bf(f0.z) | ((unsigned)f2bf(f0.w) << 16);
      v.z = (unsigned)f2bf(f1.x) | ((unsigned)f2bf(f1.y) << 16);
      v.w = (unsigned)f2bf(f1.z) | ((unsigned)f2bf(f1.w) << 16);
      *(uint4*)&As[r * 64 + ch * 8] = v;
    }
    __syncthreads();
    #pragma unroll
    for (int i = 0; i < 2; ++i){
      short8v a[4];
      #pragma unroll
      for (int mt = 0; mt < 4; ++mt)
        a[mt] = *(const short8v*)&As[(wm * 64 + mt * 16 + (lane & 15)) * 64 + i * 32 + (lane >> 4) * 8];
      #pragma unroll
      for (int nt = 0; nt < 4; ++nt){
        short8v b = Bp[((size_t)(Nb * 8 + wn * 4 + nt) * 16 + (kc * 2 + i)) * 64 + lane];
        #pragma unroll
        for (int mt = 0; mt < 4; ++mt)
          acc[mt][nt] = __builtin_amdgcn_mfma_f32_16x16x32_bf16(a[mt], b, acc[mt][nt], 0, 0, 0);
      }
    }
  }
  #pragma unroll
  for (int mt = 0; mt < 4; ++mt){
    #pragma unroll
    for (int nt = 0; nt < 4; ++nt){
      int gcol = Nb * 128 + wn * 64 + nt * 16 + (lane & 15);
      float bv = bih[gcol];
      #pragma unroll
      for (int r = 0; r < 4; ++r){
        int grow = Mb * 128 + wm * 64 + mt * 16 + (lane >> 4) * 4 + r;
        gx[(size_t)grow * NG + gcol] = f2bf(acc[mt][nt][r] + bv);
      }
    }
  }
}

// ---------------- GRU recurrence v4 ----------------
// 64 groups x 4 blocks; W_hh slice resident (AGPR-backed); single barrier per step;
// per-wave flag STORES (no RMW chain) + 32-lane parallel flag poll; gx prefetched
// one step ahead; gout written in the sync shadow.
__global__ __launch_bounds__(512, 1) void k_gru4(const unsigned short* __restrict__ gx,
                                                 const unsigned short* __restrict__ Wpk,
                                                 const float* __restrict__ bhh,
                                                 unsigned short* __restrict__ gout,
                                                 unsigned short* __restrict__ hx,   // [2][1024*512] bf16
                                                 int* __restrict__ flags){          // [GRU_G*NS*32]
  __shared__ unsigned short hbuf[2][16 * 512];   // [parity][16 k-frags of 1KB]
  int tid = threadIdx.x; int lane = tid & 63; int nh = tid >> 6;   // wave 0..7
  int bid = blockIdx.x; int g = bid & 63; int s = bid >> 6;        // group, slice
  int colg = lane & 15;
  int rowg = lane >> 4;
  int c_h = s * 128 + nh * 16 + colg;   // this lane's h column
  int b0 = g * 16;                      // group batch base

  for (int i = tid; i < 16 * 512; i += 512) hbuf[0][i] = 0;

  // resident W_hh B-fragments: 3 gate tiles x 16 k-frags = 192 regs (AGPR-backed)
  short8v wf[3][16];
  const short8v* Wp = (const short8v*)Wpk;
  #pragma unroll
  for (int gg = 0; gg < 3; ++gg){
    int ntile = gg * 32 + s * 8 + nh;
    #pragma unroll
    for (int kk = 0; kk < 16; ++kk)
      wf[gg][kk] = Wp[((size_t)ntile * 16 + kk) * 64 + lane];
  }
  float bR = bhh[c_h], bZ = bhh[512 + c_h], bN = bhh[1024 + c_h];
  float hreg[4] = {0.f, 0.f, 0.f, 0.f};

  // preload gx for t=0
  unsigned short cxr[4], cxz[4], cxn[4];
  #pragma unroll
  for (int r = 0; r < 4; ++r){
    const unsigned short* gp = gx + ((size_t)(b0 + rowg * 4 + r) * NS + 0) * NG;
    cxr[r] = gp[c_h]; cxz[r] = gp[512 + c_h]; cxn[r] = gp[1024 + c_h];
  }
  __syncthreads();

  #pragma unroll 1
  for (int t = 0; t < NS; ++t){
    int par = t & 1;
    const unsigned short* hr = hbuf[par];
    // prefetch gx for t+1 (independent; latency hidden under MFMA+sync)
    unsigned short nxr[4], nxz[4], nxn[4];
    if (t + 1 < NS){
      #pragma unroll
      for (int r = 0; r < 4; ++r){
        const unsigned short* gp = gx + ((size_t)(b0 + rowg * 4 + r) * NS + (t + 1)) * NG;
        nxr[r] = gp[c_h]; nxz[r] = gp[512 + c_h]; nxn[r] = gp[1024 + c_h];
      }
    }
    // gh = h @ Whh_slice^T
    f32x4 acc0 = (f32x4){0.f,0.f,0.f,0.f}, acc1 = acc0, acc2 = acc0;
    #pragma unroll
    for (int kc = 0; kc < 16; ++kc){
      short8v a = *(const short8v*)&hr[kc * 512 + lane * 8];
      acc0 = __builtin_amdgcn_mfma_f32_16x16x32_bf16(a, wf[0][kc], acc0, 0, 0, 0);
      acc1 = __builtin_amdgcn_mfma_f32_16x16x32_bf16(a, wf[1][kc], acc1, 0, 0, 0);
      acc2 = __builtin_amdgcn_mfma_f32_16x16x32_bf16(a, wf[2][kc], acc2, 0, 0, 0);
    }
    // activations; h kept in f32 regs across steps
    unsigned short hnew[4];
    #pragma unroll
    for (int r = 0; r < 4; ++r){
      float rr = sigm(bf2f(cxr[r]) + acc0[r] + bR);
      float zz = sigm(bf2f(cxz[r]) + acc1[r] + bZ);
      float nn = tanhfast(bf2f(cxn[r]) + rr * (acc2[r] + bN));
      float h = nn + zz * (hreg[r] - nn);
      hreg[r] = h;
      hnew[r] = f2bf(h);
    }

    if (t + 1 < NS){
      unsigned short* hxp = hx + (size_t)par * (1024 * 512);
      // paired 4B coherent stores (lane colg even stores [c, c+1])
      #pragma unroll
      for (int r = 0; r < 4; ++r){
        unsigned hv = (unsigned)hnew[r];
        unsigned ov = (unsigned)(unsigned short)__shfl_xor((int)hv, 1, 64);
        if (!(colg & 1)){
          unsigned v = hv | (ov << 16);
          __hip_atomic_store((unsigned*)(hxp + (size_t)(b0 + rowg * 4 + r) * 512 + c_h), v,
                             __ATOMIC_RELAXED, __HIP_MEMORY_SCOPE_AGENT);
        }
      }
      asm volatile("s_waitcnt vmcnt(0)" ::: "memory");
      if (lane == 0)
        __hip_atomic_store(&flags[(g * NS + t) * 32 + s * 8 + nh], 1,
                           __ATOMIC_RELAXED, __HIP_MEMORY_SCOPE_AGENT);
      // gout write overlaps the sync
      #pragma unroll
      for (int r = 0; r < 4; ++r)
        gout[((size_t)(b0 + rowg * 4 + r) * NS + t) * ND + c_h] = hnew[r];
      // parallel poll of all 32 wave-flags
      const int* fb = flags + (g * NS + t) * 32;
      int ready;
      do {
        int fv = (lane < 32) ? __hip_atomic_load(&fb[lane], __ATOMIC_RELAXED, __HIP_MEMORY_SCOPE_AGENT) : 1;
        ready = __all(fv != 0);
      } while (!ready);
      asm volatile("" ::: "memory");
      // reload full h_t: wave nh loads k-frags nh and 8+nh
      const unsigned long long* hxq = (const unsigned long long*)hxp;
      unsigned short* hw = hbuf[par ^ 1];
      #pragma unroll
      for (int q = 0; q < 2; ++q){
        int kc = q * 8 + nh;
        int batch = lane & 15, kq = lane >> 4;
        size_t base = (size_t)(b0 + batch) * 128 + kc * 8 + kq * 2;
        unsigned long long u0 = __hip_atomic_load(&hxq[base],     __ATOMIC_RELAXED, __HIP_MEMORY_SCOPE_AGENT);
        unsigned long long u1 = __hip_atomic_load(&hxq[base + 1], __ATOMIC_RELAXED, __HIP_MEMORY_SCOPE_AGENT);
        unsigned long long tmp[2] = {u0, u1};
        *(uint4*)&hw[kc * 512 + lane * 8] = *(const uint4*)tmp;
      }
      __syncthreads();
    } else {
      #pragma unroll
      for (int r = 0; r < 4; ++r)
        gout[((size_t)(b0 + rowg * 4 + r) * NS + t) * ND + c_h] = hnew[r];
    }
    #pragma unroll
    for (int r = 0; r < 4; ++r){ cxr[r] = nxr[r]; cxz[r] = nxz[r]; cxn[r] = nxn[r]; }
  }
}

// ---------------- pre/GELU/scores fused GEMM: (NM x 512) @ Wg^T (256) ----------------
__global__ __launch_bounds__(512) void k_gemm_s4(const unsigned short* __restrict__ A,
                                                 const unsigned short* __restrict__ Bpk,
                                                 const float* __restrict__ tvec,
                                                 const float* __restrict__ Wsc,
                                                 const float* __restrict__ bsc,
                                                 float* __restrict__ scores){
  __shared__ unsigned short As[128 * 64];
  __shared__ float spart[4][128];
  int tid = threadIdx.x; int lane = tid & 63; int wid = tid >> 6;
  int wm = wid >> 2, wn = wid & 3;
  int Mb = blockIdx.x;
  const unsigned short* Abase = A + (size_t)Mb * 128 * ND;
  const short8v* Bp = (const short8v*)Bpk;
  f32x4 acc[4][4];
  #pragma unroll
  for (int i = 0; i < 4; ++i)
    #pragma unroll
    for (int j = 0; j < 4; ++j) acc[i][j] = (f32x4){0.f, 0.f, 0.f, 0.f};

  for (int kc = 0; kc < 8; ++kc){
    __syncthreads();
    #pragma unroll
    for (int pass = 0; pass < 2; ++pass){
      int idx = pass * 512 + tid; int r = idx >> 3, ch = idx & 7;
      uint4 v = *(const uint4*)(Abase + (size_t)r * ND + kc * 64 + ch * 8);
      *(uint4*)&As[r * 64 + ch * 8] = v;
    }
    __syncthreads();
    #pragma unroll
    for (int i = 0; i < 2; ++i){
      short8v a[4];
      #pragma unroll
      for (int mt = 0; mt < 4; ++mt)
        a[mt] = *(const short8v*)&As[(wm * 64 + mt * 16 + (lane & 15)) * 64 + i * 32 + (lane >> 4) * 8];
      #pragma unroll
      for (int nt = 0; nt < 4; ++nt){
        short8v b = Bp[((size_t)(wn * 4 + nt) * 16 + (kc * 2 + i)) * 64 + lane];
        #pragma unroll
        for (int mt = 0; mt < 4; ++mt)
          acc[mt][nt] = __builtin_amdgcn_mfma_f32_16x16x32_bf16(a[mt], b, acc[mt][nt], 0, 0, 0);
      }
    }
  }
  #pragma unroll
  for (int mt = 0; mt < 4; ++mt){
    #pragma unroll
    for (int r = 0; r < 4; ++r){
      int rowl = wm * 64 + mt * 16 + (lane >> 4) * 4 + r;
      unsigned grow = (unsigned)(Mb * 128 + rowl);
      unsigned bidx = grow / 200u;
      float rowsum = 0.f;
      #pragma unroll
      for (int nt = 0; nt < 4; ++nt){
        int gcol = wn * 64 + nt * 16 + (lane & 15);
        float pre = acc[mt][nt][r] + tvec[(size_t)bidx * NFF + gcol];
        float g = 0.5f * pre * (1.f + erff(pre * 0.70710678118654752f));
        rowsum += g * Wsc[gcol];
      }
      rowsum += __shfl_xor(rowsum, 1, 64);
      rowsum += __shfl_xor(rowsum, 2, 64);
      rowsum += __shfl_xor(rowsum, 4, 64);
      rowsum += __shfl_xor(rowsum, 8, 64);
      if ((lane & 15) == 0) spart[wn][rowl] = rowsum;
    }
  }
  __syncthreads();
  if (tid < 128){
    float s = spart[0][tid] + spart[1][tid] + spart[2][tid] + spart[3][tid] + bsc[0];
    scores[(size_t)Mb * 128 + tid] = s;
  }
}

// ---------------- softmax over S + weighted pool + concat output ----------------
__global__ void k_out(const float* __restrict__ scores, const unsigned short* __restrict__ gout,
                      const float* __restrict__ target, float* __restrict__ out){
  int b = blockIdx.x; int tid = threadIdx.x;
  __shared__ float sw[NS];
  __shared__ float red[4];
  float v = (tid < NS) ? scores[(size_t)b * NS + tid] : -3.0e38f;
  float m = v;
  #pragma unroll
  for (int off = 32; off >= 1; off >>= 1) m = fmaxf(m, __shfl_xor(m, off, 64));
  if ((tid & 63) == 0) red[tid >> 6] = m;
  __syncthreads();
  m = fmaxf(fmaxf(red[0], red[1]), fmaxf(red[2], red[3]));
  float e = (tid < NS) ? __expf(v - m) : 0.f;
  if (tid < NS) sw[tid] = e;
  float su = e;
  #pragma unroll
  for (int off = 32; off >= 1; off >>= 1) su += __shfl_xor(su, off, 64);
  __syncthreads();
  if ((tid & 63) == 0) red[tid >> 6] = su;
  __syncthreads();
  float inv = 1.f / (red[0] + red[1] + red[2] + red[3]);
  int d0 = tid * 2;
  float a0 = 0.f, a1 = 0.f;
  const unsigned short* gbase = gout + (size_t)b * NS * ND + d0;
  for (int s = 0; s < NS; ++s){
    unsigned u = *(const unsigned*)(gbase + (size_t)s * ND);
    float wgt = sw[s];
    a0 += wgt * bf2f((unsigned short)(u & 0xffffu));
    a1 += wgt * bf2f((unsigned short)(u >> 16));
  }
  out[(size_t)b * 1024 + d0] = a0 * inv;
  out[(size_t)b * 1024 + d0 + 1] = a1 * inv;
  float2 tv = *(const float2*)(target + (size_t)b * ND + d0);
  out[(size_t)b * 1024 + 512 + d0] = tv.x;
  out[(size_t)b * 1024 + 512 + d0 + 1] = tv.y;
}

extern "C" void kernel_launch(void* const* d_in, const int* in_sizes, int n_in,
                              void* d_out, int out_size, void* d_ws, size_t ws_size,
                              hipStream_t stream) {
  const float* target  = (const float*)d_in[0];
  const float* history = (const float*)d_in[1];
  const float* W_ih    = (const float*)d_in[2];
  const float* W_hh    = (const float*)d_in[3];
  const float* b_ih    = (const float*)d_in[4];
  const float* b_hh    = (const float*)d_in[5];
  const float* W_fc    = (const float*)d_in[6];
  const float* b_fc    = (const float*)d_in[7];
  const float* W_sc    = (const float*)d_in[8];
  const float* b_sc    = (const float*)d_in[9];

  char* ws = (char*)d_ws;
  size_t off = 0;
  unsigned short* gx     = (unsigned short*)(ws + off); off += 629145600ull;  // NM*1536 bf16
  unsigned short* gout   = (unsigned short*)(ws + off); off += 209715200ull;  // NM*512 bf16
  unsigned short* wih_pk = (unsigned short*)(ws + off); off += 1572864ull;
  unsigned short* whh_pk = (unsigned short*)(ws + off); off += 1572864ull;
  unsigned short* wg_pk  = (unsigned short*)(ws + off); off += 262144ull;
  float*          tvec   = (float*)(ws + off);          off += 1048576ull;
  float*          scores = (float*)(ws + off);          off += 819200ull;
  unsigned short* hx     = (unsigned short*)(ws + off); off += 2097152ull;    // [2][1024*512] bf16
  int*            flags  = (int*)(ws + off);             off += 1638400ull;    // [64*200*32]
  if (ws_size < off) return;
  float* outp = (float*)d_out;

  hipMemsetAsync(flags, 0, GRU_G * NS * 32 * sizeof(int), stream);
  k_prepack<<<384, 256, 0, stream>>>(W_ih, wih_pk, 512, 0, 96);
  k_prepack<<<384, 256, 0, stream>>>(W_hh, whh_pk, 512, 0, 96);
  k_prepack<<<64, 256, 0, stream>>>(W_fc, wg_pk, 1024, 0, 16);
  k_tvec<<<256, 256, 0, stream>>>(target, W_fc, b_fc, tvec);
  k_gemm_gx<<<dim3(12, 1600), 256, 0, stream>>>(history, wih_pk, b_ih, gx);
  k_gru4<<<256, 512, 0, stream>>>(gx, whh_pk, b_hh, gout, hx, flags);
  k_gemm_s4<<<1600, 512, 0, stream>>>(gout, wg_pk, tvec, W_sc, b_sc, scores);
  k_out<<<1024, 256, 0, stream>>>(scores, gout, target, outp);
}